// Round 18
// baseline (120.436 us; speedup 1.0000x reference)
//
#include <hip/hip_runtime.h>
#include <hip/hip_bf16.h>

// LaplaceCostNet — MI355X (gfx950), round 18.
// R17: mlp 43.4 µs ≈ DS(20)+VALU(19) summed, not overlapped -> phase convoys
// (8-wave barrier domains, 2 blocks/CU). R18: 4-wave blocks (256 thr), single
// 32 KB buffer, grid 2048 -> 4 blocks/CU, 4 independent barrier domains; same
// per-wave dataflow (64 arch VGPR, fits). (256,3) bounds = no spill risk.
//
// Workspace (bytes):
//   [4096   .. 135168)   WT bf16: row n, physical 16B chunk P = cc^(n&15),
//                        chunk cc=2ks+Hh holds pi-permuted k slots (R16 map)
//   [262144 .. +1MB)     C    fp32
//   [262144+3MB .. +4MB) Vfin fp32

typedef unsigned short ushort_t;
typedef short short8 __attribute__((ext_vector_type(8)));
typedef float floatx16 __attribute__((ext_vector_type(16)));
typedef unsigned int uintx4 __attribute__((ext_vector_type(4)));

#define HH 512
#define WW 512
#define NPIX (HH*WW)

__device__ inline unsigned int pk_bf16(float a, float b) {   // a->low16, b->high16
    __hip_bfloat162 h = __float22bfloat162_rn(float2{a, b});
    return *(unsigned int*)&h;
}
__device__ inline void async_copy16(void* lds, const void* g) {
    __builtin_amdgcn_global_load_lds(
        (const __attribute__((address_space(1))) unsigned int*)g,
        (__attribute__((address_space(3))) unsigned int*)lds, 16, 0, 0);
}

// ---------------- prep: DMA-ready swizzled + K-PERMUTED WT (R16 map) ----------------
__global__ __launch_bounds__(256) void prep_kernel(const float* __restrict__ Wh,
                                                   ushort_t* __restrict__ WT) {
    __shared__ float trans[32][129];
    const int t = threadIdx.x;
    const int l = blockIdx.x >> 2, n0 = (blockIdx.x & 3) * 32;
    const int nl = t & 31, k0 = t >> 5;            // k0 0..7
    #pragma unroll
    for (int pass = 0; pass < 16; ++pass) {
        int k = pass * 8 + k0;
        trans[nl][k] = Wh[l * 16384 + k * 128 + n0 + nl];   // coalesced in n
    }
    __syncthreads();
    #pragma unroll
    for (int c = 0; c < 2; ++c) {
        int idx = c * 256 + t;                      // 0..511 : 32 rows x 16 chunks
        int nl2 = idx >> 4, P = idx & 15;
        int n = n0 + nl2;
        int cc = P ^ (n & 15);                      // logical chunk = 2*ks + Hh
        int ks = cc >> 1, Hq = cc & 1;
        int base = (ks >> 1) * 32 + (ks & 1) * 16 + Hq * 4;   // pi base
        unsigned int w0 = pk_bf16(trans[nl2][base + 0],  trans[nl2][base + 1]);
        unsigned int w1 = pk_bf16(trans[nl2][base + 2],  trans[nl2][base + 3]);
        unsigned int w2 = pk_bf16(trans[nl2][base + 8],  trans[nl2][base + 9]);
        unsigned int w3 = pk_bf16(trans[nl2][base + 10], trans[nl2][base + 11]);
        ((uint4*)WT)[(l * 128 + n) * 16 + P] = uint4{w0, w1, w2, w3};
    }
}

// one layer K-loop from the single LDS buffer; addresses = inn[ks] + i*8192 imm
__device__ __forceinline__ void klayer(const ushort_t* __restrict__ wlds,
                                       const int (&inn)[8],
                                       const uintx4 (&fragv)[8],
                                       floatx16 (&acc)[4]) {
    #pragma unroll
    for (int i = 0; i < 4; ++i) acc[i] = (floatx16)(0.0f);
    #pragma unroll
    for (int ks = 0; ks < 8; ++ks) {
        short8 bf = __builtin_bit_cast(short8, fragv[ks]);
        #pragma unroll
        for (int i = 0; i < 4; ++i) {
            short8 av = *(const short8*)((const char*)wlds + i * 8192 + inn[ks]);
            acc[i] = __builtin_amdgcn_mfma_f32_32x32x16_bf16(av, bf, acc[i], 0, 0, 0);
        }
    }
}

// C -> next B-frags: pure in-lane relu+pack (pi-matched, no shuffles)
__device__ __forceinline__ void xform_all(uintx4 (&fragv)[8], const floatx16 (&acc)[4]) {
    #pragma unroll
    for (int ks = 0; ks < 8; ++ks) {
        const int i = ks >> 1, par = ks & 1;
        fragv[ks][0] = pk_bf16(fmaxf(acc[i][8 * par + 0], 0.0f),
                               fmaxf(acc[i][8 * par + 1], 0.0f));
        fragv[ks][1] = pk_bf16(fmaxf(acc[i][8 * par + 2], 0.0f),
                               fmaxf(acc[i][8 * par + 3], 0.0f));
        fragv[ks][2] = pk_bf16(fmaxf(acc[i][8 * par + 4], 0.0f),
                               fmaxf(acc[i][8 * par + 5], 0.0f));
        fragv[ks][3] = pk_bf16(fmaxf(acc[i][8 * par + 6], 0.0f),
                               fmaxf(acc[i][8 * par + 7], 0.0f));
    }
}

// stage one 32 KB layer with a 4-wave (256-thr) block: 8 chunks per thread
__device__ __forceinline__ void stage_layer(ushort_t* wlds, const char* src,
                                            int wave, int lane) {
    #pragma unroll
    for (int c2 = 0; c2 < 8; ++c2) {
        int base = c2 * 256 + wave * 64;            // wave-uniform chunk base
        async_copy16(&wlds[base * 8], src + (base + lane) * 16);
    }
}

// ---------------- MLP: 4-wave blocks, single 32 KB buffer, 4 blocks/CU ----------------
__global__ __launch_bounds__(256, 3) void mlp_kernel(const float* __restrict__ x,
                                                     const ushort_t* __restrict__ WT,
                                                     const float* __restrict__ benc,
                                                     const float* __restrict__ wout,
                                                     float* __restrict__ C_ws,
                                                     float* __restrict__ outbuf) {
    __shared__ __align__(16) ushort_t wlds[128 * 128];   // 32 KB: ONE layer
    const int tid = threadIdx.x;
    const int lane = tid & 63, wave = tid >> 6;
    const int m = lane & 31, Hh = lane >> 5;        // point-col, k-half
    const int p0 = blockIdx.x * 128 + wave * 32;    // this wave's 32 points

    stage_layer(wlds, (const char*)WT, wave, lane); // L0

    // per-lane byte offsets, i-independent (n&15 == m&15): computed ONCE
    int inn[8];
    #pragma unroll
    for (int ks = 0; ks < 8; ++ks)
        inn[ks] = m * 256 + ((((2 * ks + Hh) ^ (m & 15))) << 4);

    uintx4 fragv[8];                                // B-frags in pi-slot order

    // --- encoding into pi-ordered slots (R16 map: ks<4 cos, ks>=4 sin) ---
    {
        float2 xv = ((const float2*)x)[p0 + m];
        float xq0 = 0.5f + 0.5f * xv.x, xq1 = 0.5f + 0.5f * xv.y;
        #pragma unroll
        for (int ks = 0; ks < 8; ++ks) {
            const int i = ks >> 1, par = ks & 1;
            #pragma unroll
            for (int jp = 0; jp < 4; ++jp) {
                int nu = i * 32 + par * 16 + Hh * 4 + (jp & 1) * 2 + (jp >> 1) * 8;
                int f = nu & 63;                    // freq index (nu>=64 -> sin)
                float4 b = *(const float4*)&benc[2 * f];
                float t0 = __builtin_amdgcn_fractf(xq0 * b.x + xq1 * b.y);
                float t1 = __builtin_amdgcn_fractf(xq0 * b.z + xq1 * b.w);
                float v0, v1;
                if (ks < 4) { v0 = __builtin_amdgcn_cosf(t0); v1 = __builtin_amdgcn_cosf(t1); }
                else        { v0 = __builtin_amdgcn_sinf(t0); v1 = __builtin_amdgcn_sinf(t1); }
                fragv[ks][jp] = pk_bf16(v0, v1);
            }
        }
    }
    __syncthreads();                                // drains L0 DMA

    floatx16 acc[4];
    #pragma unroll 1
    for (int l = 0; l < 4; ++l) {
        klayer(wlds, inn, fragv, acc);              // layer l
        if (l == 3) break;
        __syncthreads();                            // layer-l reads done
        stage_layer(wlds, (const char*)WT + (l + 1) * 32768, wave, lane);
        xform_all(fragv, acc);                      // register-only; overlaps DMA
        __syncthreads();                            // DMA(l+1) drained
    }

    // final dot from layer-3 accumulators: n = i*32 + (r&3) + 8*(r>>2) + 4*Hh
    float s = 0.0f;
    #pragma unroll
    for (int i = 0; i < 4; ++i) {
        #pragma unroll
        for (int rq = 0; rq < 4; ++rq) {
            float4 wv = *(const float4*)&wout[i * 32 + rq * 8 + 4 * Hh];
            s += fmaxf(acc[i][rq * 4 + 0], 0.0f) * wv.x
               + fmaxf(acc[i][rq * 4 + 1], 0.0f) * wv.y
               + fmaxf(acc[i][rq * 4 + 2], 0.0f) * wv.z
               + fmaxf(acc[i][rq * 4 + 3], 0.0f) * wv.w;
        }
    }
    s += __shfl_xor(s, 32);
    if (Hh == 0) {
        C_ws[p0 + m] = s;
        outbuf[NPIX + p0 + m] = s;                  // output 1: C
    }
}

// ---------------- fused: cost (box5 + Cs + V0) + 5 Jacobi passes ----------------
__global__ __launch_bounds__(256) void fused_solve_kernel(const int* __restrict__ bt,
                                                          const float* __restrict__ bc,
                                                          const float* __restrict__ C_ws,
                                                          float* __restrict__ Vfin) {
    __shared__ float Va[30 * 32];
    __shared__ float Vb[30 * 32];
    __shared__ float Wp[30 * 32];   // free -> Cs (>=0), pinned/out -> -(bc+1)
    const int tid = threadIdx.x;
    const int gx0 = (blockIdx.x & 31) * 16 - 7, gy0 = (blockIdx.x >> 5) * 16 - 7;

    for (int c = tid; c < 30 * 32; c += 256) {
        int li = c >> 5, lj = c & 31;
        int gi = gy0 + li, gj = gx0 + lj;
        float v = 0.0f;
        if (lj < 30 && gi >= 0 && gi < HH && gj >= 0 && gj < WW) {
            int g = gi * WW + gj;
            float b = bc[g];
            if (bt[g] == 1 && b > 0.0f) v = b;
        }
        Va[c] = v;
    }
    __syncthreads();

    for (int c = tid; c < 30 * 32; c += 256) {
        int li = c >> 5, lj = c & 31;
        int gi = gy0 + li, gj = gx0 + lj;
        float w = -1.0f, v0 = 0.0f;
        if (li >= 2 && li < 28 && lj >= 2 && lj < 28 &&
            gi >= 0 && gi < HH && gj >= 0 && gj < WW) {
            int g = gi * WW + gj;
            if (bt[g] == 0) {
                float s = 0.0f;
                #pragma unroll
                for (int di = 0; di < 5; ++di)
                    #pragma unroll
                    for (int dj = 0; dj < 5; ++dj)
                        s += Va[(li + di - 2) * 32 + lj + dj - 2];
                w = fmaxf(C_ws[g], 0.0f) + s * 0.04f;
                v0 = 100.0f;
            } else {
                float b = bc[g];
                w = -b - 1.0f;
                v0 = b;
            }
        }
        Wp[c] = w;
        Vb[c] = v0;
    }
    __syncthreads();

    float* src = Vb;
    float* dst = Va;
    #pragma unroll 1
    for (int t = 0; t < 5; ++t) {
        for (int c = tid; c < 26 * 32; c += 256) {
            int li = 2 + (c >> 5), lj = c & 31;
            if (lj < 2 || lj >= 28) continue;
            float w = Wp[li * 32 + lj];
            float v;
            if (w < 0.0f) {
                v = -w - 1.0f;
            } else {
                int gi = gy0 + li, gj = gx0 + lj;
                int um = (gi > 0)      ? li - 1 : li;
                int dp = (gi < HH - 1) ? li + 1 : li;
                int lm = (gj > 0)      ? lj - 1 : lj;
                int rp = (gj < WW - 1) ? lj + 1 : lj;
                float s = src[um * 32 + lm] + src[um * 32 + lj] + src[um * 32 + rp]
                        + src[li * 32 + lm]                     + src[li * 32 + rp]
                        + src[dp * 32 + lm] + src[dp * 32 + lj] + src[dp * 32 + rp];
                v = s * 0.125f + w;
            }
            dst[li * 32 + lj] = v;
        }
        __syncthreads();
        float* tmp = src; src = dst; dst = tmp;
    }

    {
        int li = 7 + (tid >> 4), lj = 7 + (tid & 15);
        Vfin[(gy0 + li) * WW + gx0 + lj] = src[li * 32 + lj];
    }
}

// ---------------- bilinear grid sample (align_corners, border clamp) ----------------
__global__ void sample_kernel(const float* __restrict__ x,
                              const float* __restrict__ V,
                              float* __restrict__ out) {
    int idx = blockIdx.x * 256 + threadIdx.x;
    float2 g2 = ((const float2*)x)[idx];
    float ix = (g2.x + 1.0f) * 0.5f * 511.0f;
    float iy = (g2.y + 1.0f) * 0.5f * 511.0f;
    ix = fminf(fmaxf(ix, 0.0f), 511.0f);
    iy = fminf(fmaxf(iy, 0.0f), 511.0f);
    int x0 = (int)floorf(ix), y0 = (int)floorf(iy);
    int x1 = min(x0 + 1, 511), y1 = min(y0 + 1, 511);
    float wx = ix - (float)x0, wy = iy - (float)y0;
    float v00 = V[y0 * 512 + x0], v01 = V[y0 * 512 + x1];
    float v10 = V[y1 * 512 + x0], v11 = V[y1 * 512 + x1];
    float v = v00 * (1.0f - wx) * (1.0f - wy) + v01 * wx * (1.0f - wy)
            + v10 * (1.0f - wx) * wy          + v11 * wx * wy;
    out[idx] = v;   // output 0
}

extern "C" void kernel_launch(void* const* d_in, const int* in_sizes, int n_in,
                              void* d_out, int out_size, void* d_ws, size_t ws_size,
                              hipStream_t stream) {
    const float* x    = (const float*)d_in[0];
    const int*   bt   = (const int*)d_in[1];
    const float* bc   = (const float*)d_in[2];
    const float* benc = (const float*)d_in[3];
    const float* Wh   = (const float*)d_in[4];
    const float* wout = (const float*)d_in[5];

    char* ws = (char*)d_ws;
    ushort_t* WT   = (ushort_t*)(ws + 4096);
    float*    C_ws = (float*)(ws + 262144);
    float*    Vfin = (float*)(ws + 262144 + 3 * (1 << 20));
    float*    outp = (float*)d_out;

    prep_kernel<<<16, 256, 0, stream>>>(Wh, WT);
    mlp_kernel<<<2048, 256, 0, stream>>>(x, WT, benc, wout, C_ws, outp);
    fused_solve_kernel<<<1024, 256, 0, stream>>>(bt, bc, C_ws, Vfin);
    sample_kernel<<<1024, 256, 0, stream>>>(x, Vfin, outp);
}